// Round 11
// baseline (745.307 us; speedup 1.0000x reference)
//
#include <hip/hip_runtime.h>
#include <math.h>

#define N 96
#define PAD 100        // padded LDS row stride (floats)
#define T 768          // 12 waves, one workgroup, one CU
#define ITERS 50
#define LW 52          // neighbor-list width (u16 entries, padded to x4)

typedef float f2 __attribute__((ext_vector_type(2)));
typedef float f4 __attribute__((ext_vector_type(4)));
typedef unsigned short u16x4 __attribute__((ext_vector_type(4)));

// lane-group max via DPP (VALU pipe, no LDS traffic); CTRL must be constexpr
template <int CTRL>
__device__ __forceinline__ float dppmax(float m) {
    int mi = __builtin_bit_cast(int, m);
    int sw = __builtin_amdgcn_update_dpp(mi, mi, CTRL, 0xf, 0xf, true);
    return fmaxf(m, __builtin_bit_cast(float, sw));
}
#define DPP_XOR1 0xB1  // quad_perm:[1,0,3,2]
#define DPP_XOR2 0x4E  // quad_perm:[2,3,0,1]
#define DPP_SHL4 0x104 // row_shl:4 (dest l <- src l+4; OOB -> 0; data >= 0 so safe)

// Fully fused MPM, one workgroup, 3 barriers/iter.
// M-phase: t -> g=t/128 (row group, j≡g mod 6, 16 rows; wave-uniform),
//          r=t%128, q=r&7 (b in [12q,12q+12)), cs=r>>3 (cols 6cs..6cs+5).
//          W[6 cols][12 b] as 36 f2 (72 VGPRs). Per (row,col): 6 v_pk_mul_f32
//          + 5 v_pk_max_f32 + 1 fold; 8-lane combine via DPP xor1,xor2,shl4.
// Agg:     ac=t%48 -> cols 2ac,2ac+1 ; rows i = t/48 + 16k (k=0..5);
//          f2 neighbor gathers via byte-offset lists; diag X in regs.
//          (identical to the round-9 kernel -> bitwise-same output)
__global__ __launch_bounds__(T)
__attribute__((amdgpu_waves_per_eu(3, 3)))
void k_fused(const float* __restrict__ A,
             const float* __restrict__ vec,
             float* __restrict__ out) {
    __shared__ float Xs[N * PAD];            // 38400 B : X (staging B, then A)
    __shared__ float Ms[(N + 1) * PAD];      // 38800 B : full M + zero row 96
    __shared__ unsigned short lst[N * LW];   //  9984 B : nbr BYTE offsets (j*400)
    __shared__ short cnt4[N];                // padded counts (multiple of 4)
    __shared__ float degA[N];
    __shared__ float degB[N];
    __shared__ float red[T / 64];

    const int t = threadIdx.x;
    const int g = t / 128;                 // M row group 0..5 (wave-uniform)
    const int r = t % 128;
    const int q = r & 7;                   // b-eighth
    const int cs = r >> 3;                 // col sextet 0..15
    const int ac = t % 48;                 // agg column-pair id
    const int ri = t / 48;                 // agg row base 0..15
    const float s1 = 1.0f / (1.0f + expf(-1.0f));   // sigmoid(1) = diag of B
    const float s1s1 = s1 * s1;

    // ---- setup phase 0: B -> Xs (staging) ----
#pragma unroll
    for (int k = 0; k < 12; ++k) {
        int e = t + k * T;
        int rr = e / N, cc = e % N;
        float logit;
        if (rr == cc) {
            logit = 1.0f;
        } else {
            int i = rr < cc ? rr : cc;
            int j = rr < cc ? cc : rr;
            int idx = i * 95 - (i * (i - 1)) / 2 + (j - i - 1);
            logit = vec[idx];
        }
        Xs[rr * PAD + cc] = 1.0f / (1.0f + expf(-logit));
    }
    __syncthreads();

    // W tile as f2 pairs (B symmetric: col a == row a), diag = 0
    f2 Wp[6][6];
#pragma unroll
    for (int c = 0; c < 6; ++c) {
        int col = 6 * cs + c;
#pragma unroll
        for (int bp = 0; bp < 6; ++bp) {
            int b = 12 * q + 2 * bp;
            float w0 = (b == col) ? 0.f : Xs[b * PAD + col] * s1s1;
            float w1 = (b + 1 == col) ? 0.f : Xs[(b + 1) * PAD + col] * s1s1;
            Wp[c][bp] = (f2){w0, w1};
        }
    }

    if (t < N) {
        float s = 0.f;
        for (int rr = 0; rr < N; ++rr) s += Xs[rr * PAD + t];
        degB[t] = s;
    }
    __syncthreads();   // all reads of B done

    // ---- setup phase 1: A -> Xs (staging) ----
#pragma unroll
    for (int k = 0; k < 12; ++k) {
        int e = t + k * T;
        Xs[(e / N) * PAD + (e % N)] = A[e];
    }
    __syncthreads();

    if (t < N) {
        float s = 0.f;
        for (int rr = 0; rr < N; ++rr) s += Xs[rr * PAD + t];   // A symmetric
        degA[t] = s;
    } else if (t < 2 * N) {
        int i = t - N;
        int c_ = 0;
        for (int j = 0; j < N; ++j) {
            if (j != i && Xs[j * PAD + i] > 0.5f)                // A symmetric
                lst[i * LW + c_++] = (unsigned short)(j * PAD * 4);
        }
        while (c_ & 3) lst[i * LW + c_++] = (unsigned short)(N * PAD * 4);
        cnt4[i] = (short)c_;
    }
    // zero row 96 of Ms (pad target) — written once, never overwritten
    if (t < PAD) Ms[N * PAD + t] = 0.0f;
    __syncthreads();   // lists/degs ready, Xs(A) reads done

    // node-sim coefficients + register-resident diag X (agg: 6 rows x 2 cols)
    f2 ns2[6], x2[6];
#pragma unroll
    for (int k = 0; k < 6; ++k) {
        int i = ri + 16 * k;
        ns2[k] = (f2){s1 / (fabsf(degA[i] - degB[2 * ac]) + 1.0f),
                      s1 / (fabsf(degA[i] - degB[2 * ac + 1]) + 1.0f)};
        x2[k] = (f2){1.0f / 96.0f, 1.0f / 96.0f};
    }

    // X0 = 1/96 everywhere (||X0|| = 1 exactly)
#pragma unroll
    for (int k = 0; k < 12; ++k) {
        int e = t + k * T;
        Xs[(e / N) * PAD + (e % N)] = (1.0f / 96.0f);
    }
    __syncthreads();

    const float* xbase = &Xs[g * PAD + 12 * q];      // row jj -> + jj*6*PAD
    const char* MsaB = (const char*)Ms + 8 * ac;     // agg col-pair base (bytes)

    // ---- main loop ----
    for (int it = 0; it < ITERS; ++it) {
        // M-phase: 16 rows j = 6*jj + g, 3 const-offset b128 reads per row
#pragma unroll 4
        for (int jj = 0; jj < 16; ++jj) {
            const float* xr = xbase + jj * 6 * PAD;
            f4 Xa = *(const f4*)(xr);
            f4 Xb = *(const f4*)(xr + 4);
            f4 Xc = *(const f4*)(xr + 8);
            f2 xp0 = (f2){Xa.x, Xa.y}, xp1 = (f2){Xa.z, Xa.w};
            f2 xp2 = (f2){Xb.x, Xb.y}, xp3 = (f2){Xb.z, Xb.w};
            f2 xp4 = (f2){Xc.x, Xc.y}, xp5 = (f2){Xc.z, Xc.w};
            float mc[6];
#pragma unroll
            for (int c = 0; c < 6; ++c) {
                f2 p = Wp[c][0] * xp0;                               // v_pk_mul_f32
                p = __builtin_elementwise_max(p, Wp[c][1] * xp1);    // v_pk_max_f32
                p = __builtin_elementwise_max(p, Wp[c][2] * xp2);
                p = __builtin_elementwise_max(p, Wp[c][3] * xp3);
                p = __builtin_elementwise_max(p, Wp[c][4] * xp4);
                p = __builtin_elementwise_max(p, Wp[c][5] * xp5);
                float m = fmaxf(p.x, p.y);
                // exact 8-lane max combine, all on the VALU pipe
                m = dppmax<DPP_XOR1>(m);
                m = dppmax<DPP_XOR2>(m);
                m = dppmax<DPP_SHL4>(m);
                mc[c] = m;
            }
            if (q == 0) {
                float* dst = &Ms[(6 * jj + g) * PAD + 6 * cs];
                *(f2*)(dst)     = (f2){mc[0], mc[1]};
                *(f2*)(dst + 2) = (f2){mc[2], mc[3]};
                *(f2*)(dst + 4) = (f2){mc[4], mc[5]};
            }
        }
        __syncthreads();   // (A) Ms complete; all Xs reads done

        // aggregate (diag from regs, then ascending-j neighbors — exact order)
        f2 y2[6];
#pragma unroll
        for (int k = 0; k < 6; ++k) {
            int i = ri + 16 * k;
            f2 acc = x2[k] * ns2[k];
            int nch = (int)cnt4[i] >> 2;
            const unsigned short* lp = &lst[i * LW];
            for (int cc = 0; cc < nch; ++cc) {
                u16x4 o = *(const u16x4*)(lp + 4 * cc);
                acc += *(const f2*)(MsaB + o.x);
                acc += *(const f2*)(MsaB + o.y);
                acc += *(const f2*)(MsaB + o.z);
                acc += *(const f2*)(MsaB + o.w);
            }
            y2[k] = acc;
        }

        // block-wide norm (deterministic fixed tree)
        float ss = 0.f;
#pragma unroll
        for (int k = 0; k < 6; ++k) {
            ss = fmaf(y2[k].x, y2[k].x, ss);
            ss = fmaf(y2[k].y, y2[k].y, ss);
        }
#pragma unroll
        for (int mm = 1; mm < 64; mm <<= 1) ss += __shfl_xor(ss, mm, 64);
        if ((t & 63) == 0) red[t >> 6] = ss;
        __syncthreads();   // (B) red ready; all Ms reads done
        float s = 0.f;
#pragma unroll
        for (int w2 = 0; w2 < T / 64; ++w2) s += red[w2];
        float inv = 1.0f / sqrtf(s);
        f2 inv2 = (f2){inv, inv};
#pragma unroll
        for (int k = 0; k < 6; ++k) {
            int i = ri + 16 * k;
            f2 xn = y2[k] * inv2;
            x2[k] = xn;
            *(f2*)&Xs[i * PAD + 2 * ac] = xn;
        }
        __syncthreads();   // (C) Xs ready for next iter; Ms safe to overwrite
    }

    // ---- output ----
#pragma unroll
    for (int k = 0; k < 12; ++k) {
        int e = t + k * T;
        out[e] = Xs[(e / N) * PAD + (e % N)];
    }
}

extern "C" void kernel_launch(void* const* d_in, const int* in_sizes, int n_in,
                              void* d_out, int out_size, void* d_ws, size_t ws_size,
                              hipStream_t stream) {
    const float* A = (const float*)d_in[0];     // A_gt, 96*96
    const float* vec = (const float*)d_in[1];   // vec_logits, 4560
    float* out = (float*)d_out;
    k_fused<<<1, T, 0, stream>>>(A, vec, out);
}